// Round 9
// baseline (222.368 us; speedup 1.0000x reference)
//
#include <hip/hip_runtime.h>
#include <hip/hip_bf16.h>
#include <math.h>

// GCN 2-layer forward, round-9: hierarchical radix sort to CSR.
//   pass 1: chunk-scatter into 49 super-buckets (2048 nodes, dst>>11):
//           782 blocks AND ~84-edge (334B) runs -> write-combinable + occupied.
//           Bases via global histogram + tiny scan; per-chunk reservation via
//           one global atomicAdd per (block, super-bucket).
//   pass 2: one 1024-thread block per super-bucket: full node-level counting
//           sort in LDS (2048 counters + pairwise Hillis-Steele scan) ->
//           rp[], dinv[], pure-src packed2[]. All traffic in a ~260KB region.
// Aggregation (r7, proven): register-accumulated CSR walk, bf16 h1 table,
// layer-2 transform fused into agg1 epilogue, log_softmax into agg2.
// Assumes N <= 131072 (src packed in 17 bits; harness N = 100000).

#define F_IN 128
#define H1 16
#define C_OUT 2
#define SBS 2048         // nodes per super-bucket
#define LOG_SBS 11
#define NSB_MAX 64
#define CH1 4096         // edges per chunk in count/scatter

typedef int ix4 __attribute__((ext_vector_type(4)));

__device__ __forceinline__ float bflo(unsigned u) { return __uint_as_float(u << 16); }
__device__ __forceinline__ float bfhi(unsigned u) { return __uint_as_float(u & 0xFFFF0000u); }

// ---- global histogram of super-buckets ----
__global__ __launch_bounds__(256) void k_count_sb(
    const int* __restrict__ dst0, int* __restrict__ gh, int E, int NSB) {
    __shared__ int sc[NSB_MAX];
    int t = threadIdx.x;
    if (t < NSB) sc[t] = 0;
    __syncthreads();
    int e0 = blockIdx.x * CH1, e1 = min(e0 + CH1, E);
    int n4 = (e1 - e0) >> 2;
    const ix4* d4 = (const ix4*)(dst0 + e0);
    for (int i = t; i < n4; i += 256) {
        ix4 d = __builtin_nontemporal_load(&d4[i]);
        atomicAdd(&sc[((unsigned)d.x) >> LOG_SBS], 1);
        atomicAdd(&sc[((unsigned)d.y) >> LOG_SBS], 1);
        atomicAdd(&sc[((unsigned)d.z) >> LOG_SBS], 1);
        atomicAdd(&sc[((unsigned)d.w) >> LOG_SBS], 1);
    }
    for (int e = e0 + n4 * 4 + t; e < e1; e += 256)
        atomicAdd(&sc[((unsigned)dst0[e]) >> LOG_SBS], 1);
    __syncthreads();
    if (t < NSB && sc[t]) atomicAdd(&gh[t], sc[t]);
}

// ---- tiny scan: base_sb[0..NSB], init gcur_sb, rp[N]=E ----
__global__ void k_scan_sb(const int* __restrict__ gh, int* __restrict__ base_sb,
                          int* __restrict__ gcur_sb, int* __restrict__ rp,
                          int NSB, int N, int E) {
    if (threadIdx.x == 0) {
        int run = 0;
        for (int i = 0; i < NSB; ++i) {
            base_sb[i] = run;
            gcur_sb[i] = run;
            run += gh[i];
        }
        base_sb[NSB] = run;   // == E
        rp[N] = E;            // safety for N at an SB boundary
    }
}

// ---- pass 1: scatter (src | dst_local_sb<<17) into super-bucket regions ----
__global__ __launch_bounds__(256) void k_scat1(
    const int* __restrict__ src0, const int* __restrict__ dst0,
    int* __restrict__ gcur_sb, unsigned* __restrict__ packed1, int E, int NSB) {
    __shared__ int hist[NSB_MAX];
    __shared__ int lcur[NSB_MAX];
    int t = threadIdx.x;
    if (t < NSB) hist[t] = 0;
    __syncthreads();
    int e0 = blockIdx.x * CH1, e1 = min(e0 + CH1, E);
    int n4 = (e1 - e0) >> 2;
    const ix4* d4 = (const ix4*)(dst0 + e0);
    const ix4* s4 = (const ix4*)(src0 + e0);
    for (int i = t; i < n4; i += 256) {
        ix4 d = __builtin_nontemporal_load(&d4[i]);
        atomicAdd(&hist[((unsigned)d.x) >> LOG_SBS], 1);
        atomicAdd(&hist[((unsigned)d.y) >> LOG_SBS], 1);
        atomicAdd(&hist[((unsigned)d.z) >> LOG_SBS], 1);
        atomicAdd(&hist[((unsigned)d.w) >> LOG_SBS], 1);
    }
    for (int e = e0 + n4 * 4 + t; e < e1; e += 256)
        atomicAdd(&hist[((unsigned)dst0[e]) >> LOG_SBS], 1);
    __syncthreads();
    if (t < NSB) {
        int h = hist[t];
        lcur[t] = h ? atomicAdd(&gcur_sb[t], h) : 0;
    }
    __syncthreads();
    for (int i = t; i < n4; i += 256) {
        ix4 d = __builtin_nontemporal_load(&d4[i]);
        ix4 s = __builtin_nontemporal_load(&s4[i]);
        {
            unsigned dd = (unsigned)d.x;
            int pos = atomicAdd(&lcur[dd >> LOG_SBS], 1);
            packed1[pos] = (unsigned)s.x | ((dd & (SBS - 1)) << 17);
        }
        {
            unsigned dd = (unsigned)d.y;
            int pos = atomicAdd(&lcur[dd >> LOG_SBS], 1);
            packed1[pos] = (unsigned)s.y | ((dd & (SBS - 1)) << 17);
        }
        {
            unsigned dd = (unsigned)d.z;
            int pos = atomicAdd(&lcur[dd >> LOG_SBS], 1);
            packed1[pos] = (unsigned)s.z | ((dd & (SBS - 1)) << 17);
        }
        {
            unsigned dd = (unsigned)d.w;
            int pos = atomicAdd(&lcur[dd >> LOG_SBS], 1);
            packed1[pos] = (unsigned)s.w | ((dd & (SBS - 1)) << 17);
        }
    }
    for (int e = e0 + n4 * 4 + t; e < e1; e += 256) {
        unsigned dd = (unsigned)dst0[e];
        int pos = atomicAdd(&lcur[dd >> LOG_SBS], 1);
        packed1[pos] = (unsigned)src0[e] | ((dd & (SBS - 1)) << 17);
    }
}

// ---- pass 2: per super-bucket node-level counting sort -> rp, dinv, packed2 ----
__global__ __launch_bounds__(1024) void k_sort_sb(
    const unsigned* __restrict__ packed1, const int* __restrict__ base_sb,
    int* __restrict__ packed2, int* __restrict__ rp,
    float* __restrict__ dinv, int N) {
    __shared__ int cnt[SBS];
    __shared__ int s2[1024];
    __shared__ int cur[SBS];
    int b = blockIdx.x, t = threadIdx.x;
    int e0 = base_sb[b], e1 = base_sb[b + 1];
    cnt[t] = 0; cnt[t + 1024] = 0;
    __syncthreads();
    for (int e = e0 + t; e < e1; e += 1024)
        atomicAdd(&cnt[packed1[e] >> 17], 1);
    __syncthreads();
    int c0 = cnt[2 * t], c1 = cnt[2 * t + 1];
    s2[t] = c0 + c1;
    __syncthreads();
    for (int off = 1; off < 1024; off <<= 1) {
        int v = (t >= off) ? s2[t - off] : 0;
        __syncthreads();
        s2[t] += v;
        __syncthreads();
    }
    int ep = t ? s2[t - 1] : 0;
    int node0 = b << LOG_SBS;
    int p0 = e0 + ep, p1 = e0 + ep + c0;
    cur[2 * t] = p0; cur[2 * t + 1] = p1;
    int n0 = node0 + 2 * t, n1 = n0 + 1;
    if (n0 <= N) rp[n0] = p0;
    if (n1 <= N) rp[n1] = p1;
    if (n0 < N) dinv[n0] = rsqrtf((float)(c0 + 1));   // +1 self-loop
    if (n1 < N) dinv[n1] = rsqrtf((float)(c1 + 1));
    __syncthreads();
    for (int e = e0 + t; e < e1; e += 1024) {
        unsigned p = packed1[e];                       // L2-hot re-read
        int pos = atomicAdd(&cur[p >> 17], 1);
        packed2[pos] = (int)(p & 0x1FFFF);             // pure src index
    }
}

// ---- layer 1 GEMM: h1b = bf16((x@W1)*dinv) ----
__global__ __launch_bounds__(256) void k_gemm1(
    const float* __restrict__ x, const float* __restrict__ W1,
    const float* __restrict__ dinv, __hip_bfloat16* __restrict__ h1b, int N) {
    __shared__ float w[F_IN * H1];    // 8 KB
    __shared__ float xt[16 * F_IN];   // 8 KB
    int tid = threadIdx.x;
    int node0 = blockIdx.x * 16;

    const float4* W14 = (const float4*)W1;
    float4* w4 = (float4*)w;
    for (int i = tid; i < F_IN * H1 / 4; i += 256) w4[i] = W14[i];

    const float4* x4 = (const float4*)x;
    float4* xt4 = (float4*)xt;
    for (int i = tid; i < 16 * F_IN / 4; i += 256) {
        int r = i >> 5;
        int node = node0 + r;
        xt4[i] = (node < N) ? x4[(size_t)node * 32 + (i & 31)]
                            : make_float4(0.f, 0.f, 0.f, 0.f);
    }
    __syncthreads();

    int nsub = tid >> 4, f = tid & 15;
    int node = node0 + nsub;
    if (node < N) {
        const float* xr = xt + nsub * F_IN;
        float acc = 0.0f;
        #pragma unroll 16
        for (int k = 0; k < F_IN; ++k)
            acc = fmaf(xr[k], w[k * H1 + f], acc);
        h1b[(size_t)node * H1 + f] = __float2bfloat16(acc * dinv[node]);
    }
}

// ---- layer 1 aggregate + layer 2 transform, thread per (node, feature-half) ----
__global__ __launch_bounds__(256) void k_agg1(
    const int* __restrict__ packed2, const int* __restrict__ rp,
    const __hip_bfloat16* __restrict__ h1b, const float* __restrict__ dinv,
    const float* __restrict__ b1, const float* __restrict__ W2,
    float* __restrict__ h2s, int N) {
    int tid = blockIdx.x * 256 + threadIdx.x;
    int n = tid >> 1, q = tid & 1;
    if (n >= N) return;
    const uint4* h4 = (const uint4*)h1b;
    float a[8];
    {   // self-loop init: own pre-scaled row half
        uint4 s = h4[(size_t)n * 2 + q];
        a[0] = bflo(s.x); a[1] = bfhi(s.x); a[2] = bflo(s.y); a[3] = bfhi(s.y);
        a[4] = bflo(s.z); a[5] = bfhi(s.z); a[6] = bflo(s.w); a[7] = bfhi(s.w);
    }
    int e = rp[n], e1 = rp[n + 1];
    for (; e + 4 <= e1; e += 4) {
        int p0 = packed2[e + 0];
        int p1 = packed2[e + 1];
        int p2 = packed2[e + 2];
        int p3 = packed2[e + 3];
        uint4 v0 = h4[(size_t)p0 * 2 + q];
        uint4 v1 = h4[(size_t)p1 * 2 + q];
        uint4 v2 = h4[(size_t)p2 * 2 + q];
        uint4 v3 = h4[(size_t)p3 * 2 + q];
        a[0] += bflo(v0.x); a[1] += bfhi(v0.x); a[2] += bflo(v0.y); a[3] += bfhi(v0.y);
        a[4] += bflo(v0.z); a[5] += bfhi(v0.z); a[6] += bflo(v0.w); a[7] += bfhi(v0.w);
        a[0] += bflo(v1.x); a[1] += bfhi(v1.x); a[2] += bflo(v1.y); a[3] += bfhi(v1.y);
        a[4] += bflo(v1.z); a[5] += bfhi(v1.z); a[6] += bflo(v1.w); a[7] += bfhi(v1.w);
        a[0] += bflo(v2.x); a[1] += bfhi(v2.x); a[2] += bflo(v2.y); a[3] += bfhi(v2.y);
        a[4] += bflo(v2.z); a[5] += bfhi(v2.z); a[6] += bflo(v2.w); a[7] += bfhi(v2.w);
        a[0] += bflo(v3.x); a[1] += bfhi(v3.x); a[2] += bflo(v3.y); a[3] += bfhi(v3.y);
        a[4] += bflo(v3.z); a[5] += bfhi(v3.z); a[6] += bflo(v3.w); a[7] += bfhi(v3.w);
    }
    for (; e < e1; ++e) {
        int p = packed2[e];
        uint4 v = h4[(size_t)p * 2 + q];
        a[0] += bflo(v.x); a[1] += bfhi(v.x); a[2] += bflo(v.y); a[3] += bfhi(v.y);
        a[4] += bflo(v.z); a[5] += bfhi(v.z); a[6] += bflo(v.w); a[7] += bfhi(v.w);
    }
    float dv = dinv[n];
    float c0 = 0.f, c1 = 0.f;
    #pragma unroll
    for (int j = 0; j < 8; ++j) {
        int f = q * 8 + j;
        float vv = fmaxf(fmaf(a[j], dv, b1[f]), 0.f);
        c0 = fmaf(vv, W2[f * C_OUT + 0], c0);
        c1 = fmaf(vv, W2[f * C_OUT + 1], c1);
    }
    c0 += __shfl_xor(c0, 1);
    c1 += __shfl_xor(c1, 1);
    if (q == 0)
        ((float2*)h2s)[n] = make_float2(c0 * dv, c1 * dv);
}

// ---- layer 2 aggregate + log_softmax, thread per node ----
__global__ __launch_bounds__(256) void k_agg2(
    const int* __restrict__ packed2, const int* __restrict__ rp,
    const float* __restrict__ h2s, const float* __restrict__ dinv,
    const float* __restrict__ b2, float* __restrict__ out, int N) {
    int n = blockIdx.x * 256 + threadIdx.x;
    if (n >= N) return;
    const float2* h2 = (const float2*)h2s;
    float2 self = h2[n];
    float a0 = self.x, a1 = self.y;
    int e = rp[n], e1 = rp[n + 1];
    for (; e + 4 <= e1; e += 4) {
        int p0 = packed2[e + 0];
        int p1 = packed2[e + 1];
        int p2 = packed2[e + 2];
        int p3 = packed2[e + 3];
        float2 v0 = h2[p0], v1 = h2[p1], v2 = h2[p2], v3 = h2[p3];
        a0 += v0.x + v1.x + v2.x + v3.x;
        a1 += v0.y + v1.y + v2.y + v3.y;
    }
    for (; e < e1; ++e) {
        float2 v = h2[packed2[e]];
        a0 += v.x; a1 += v.y;
    }
    float dv = dinv[n];
    a0 = fmaf(a0, dv, b2[0]);
    a1 = fmaf(a1, dv, b2[1]);
    float m = fmaxf(a0, a1);
    float lse = m + logf(expf(a0 - m) + expf(a1 - m));
    ((float2*)out)[n] = make_float2(a0 - lse, a1 - lse);
}

extern "C" void kernel_launch(void* const* d_in, const int* in_sizes, int n_in,
                              void* d_out, int out_size, void* d_ws, size_t ws_size,
                              hipStream_t stream) {
    const float* x  = (const float*)d_in[0];
    const int* ei   = (const int*)d_in[1];
    const float* W1 = (const float*)d_in[2];
    const float* b1 = (const float*)d_in[3];
    const float* W2 = (const float*)d_in[4];
    const float* b2 = (const float*)d_in[5];
    float* out = (float*)d_out;

    const int N = in_sizes[0] / F_IN;     // 100000 (assumed <= 131072)
    const int E = in_sizes[1] / 2;        // 3200000
    const int* src0 = ei;
    const int* dst0 = ei + E;

    const int NSB = (N + SBS - 1) >> LOG_SBS;    // 49
    const int nblk = (E + CH1 - 1) / CH1;        // 782

    // workspace layout (float units), 16B-aligned chunks
    size_t off = 0;
    float* wsf = (float*)d_ws;
    auto take = [&](size_t nf) { float* p = wsf + off; off += (nf + 3) & ~(size_t)3; return p; };
    float* dinv    = take(N);
    __hip_bfloat16* h1b = (__hip_bfloat16*)take((size_t)N * H1 / 2);
    float* h2s     = take((size_t)N * C_OUT);
    unsigned* packed1 = (unsigned*)take(E);
    int*   packed2 = (int*)take(E);
    int*   gh      = (int*)take(NSB_MAX);
    int*   base_sb = (int*)take(NSB_MAX + 1);
    int*   gcur_sb = (int*)take(NSB_MAX);
    int*   rp      = (int*)take(N + 1);

    hipMemsetAsync(gh, 0, NSB * sizeof(int), stream);
    k_count_sb<<<nblk, 256, 0, stream>>>(dst0, gh, E, NSB);
    k_scan_sb<<<1, 64, 0, stream>>>(gh, base_sb, gcur_sb, rp, NSB, N, E);
    k_scat1<<<nblk, 256, 0, stream>>>(src0, dst0, gcur_sb, packed1, E, NSB);
    k_sort_sb<<<NSB, 1024, 0, stream>>>(packed1, base_sb, packed2, rp, dinv, N);
    k_gemm1<<<(N + 15) / 16, 256, 0, stream>>>(x, W1, dinv, h1b, N);
    k_agg1<<<(2 * N + 255) / 256, 256, 0, stream>>>(packed2, rp, h1b, dinv, b1, W2, h2s, N);
    k_agg2<<<(N + 255) / 256, 256, 0, stream>>>(packed2, rp, h2s, dinv, b2, out, N);
}

// Round 10
// 181.750 us; speedup vs baseline: 1.2235x; 1.2235x over previous
//
#include <hip/hip_runtime.h>
#include <hip/hip_bf16.h>
#include <math.h>

// GCN 2-layer forward, round-10: single-level super-bucket radix (SBS=1024,
// NSB=98) balancing BOTH constraints learned in r7-r9:
//   - scat1 runs = ~42 edges (168B): every 64B line of packed1 is written by
//     exactly one block -> ~1x write amplification (r8 lesson), at 782 blocks
//     of parallelism (r7 lesson).
//   - sort_sb: 98 blocks x 16 waves, per-block footprint 256KB -> fits per-XCD
//     L2 even when dispatch clusters blocks (r9 lesson: 49 blocks x 520KB
//     thrashed partial lines, 5.3x write amp).
// No count prepass: fixed-capacity SB regions (CAP = expected + 12% + 2048,
// ~22 sigma), per-chunk reservation via one global atomicAdd per (block, SB);
// sort_sb redundantly recomputes the 98-value compaction scan (free).
// Aggregation unchanged from r7/r9 (register-accumulated CSR, bf16 h1 table,
// fused layer-2 transform / log_softmax).
// Assumes N <= 131072 (NSB_MAX=128; src packed in 22 bits).

#define F_IN 128
#define H1 16
#define C_OUT 2
#define SBS 1024         // nodes per super-bucket
#define LOG_SBS 10
#define NSB_MAX 128
#define SRC_MASK 0x3FFFFF   // 22-bit src
#define CH1 4096         // edges per chunk in scat1

typedef int ix4 __attribute__((ext_vector_type(4)));

__device__ __forceinline__ float bflo(unsigned u) { return __uint_as_float(u << 16); }
__device__ __forceinline__ float bfhi(unsigned u) { return __uint_as_float(u & 0xFFFF0000u); }

// ---- init: per-SB write cursors at region bases; rp[N] fallback ----
__global__ void k_init(int* __restrict__ gcur_sb, int* __restrict__ rp,
                       int NSB, int CAP, int N, int E) {
    int t = threadIdx.x;
    if (t < NSB) gcur_sb[t] = t * CAP;
    if (t == 0) rp[N] = E;
}

// ---- pass 1: chunk-scatter (src | dst_local<<22) into SB regions ----
__global__ __launch_bounds__(256) void k_scat1(
    const int* __restrict__ src0, const int* __restrict__ dst0,
    int* __restrict__ gcur_sb, unsigned* __restrict__ packed1, int E, int NSB) {
    __shared__ int hist[NSB_MAX];
    __shared__ int lcur[NSB_MAX];
    int t = threadIdx.x;
    if (t < NSB) hist[t] = 0;
    __syncthreads();
    int e0 = blockIdx.x * CH1, e1 = min(e0 + CH1, E);
    int n4 = (e1 - e0) >> 2;
    const ix4* d4 = (const ix4*)(dst0 + e0);
    const ix4* s4 = (const ix4*)(src0 + e0);
    for (int i = t; i < n4; i += 256) {
        ix4 d = __builtin_nontemporal_load(&d4[i]);
        atomicAdd(&hist[((unsigned)d.x) >> LOG_SBS], 1);
        atomicAdd(&hist[((unsigned)d.y) >> LOG_SBS], 1);
        atomicAdd(&hist[((unsigned)d.z) >> LOG_SBS], 1);
        atomicAdd(&hist[((unsigned)d.w) >> LOG_SBS], 1);
    }
    for (int e = e0 + n4 * 4 + t; e < e1; e += 256)
        atomicAdd(&hist[((unsigned)dst0[e]) >> LOG_SBS], 1);
    __syncthreads();
    if (t < NSB) {
        int h = hist[t];
        lcur[t] = h ? atomicAdd(&gcur_sb[t], h) : 0;
    }
    __syncthreads();
    for (int i = t; i < n4; i += 256) {
        ix4 d = __builtin_nontemporal_load(&d4[i]);
        ix4 s = __builtin_nontemporal_load(&s4[i]);
        {
            unsigned dd = (unsigned)d.x;
            int pos = atomicAdd(&lcur[dd >> LOG_SBS], 1);
            packed1[pos] = (unsigned)s.x | ((dd & (SBS - 1)) << 22);
        }
        {
            unsigned dd = (unsigned)d.y;
            int pos = atomicAdd(&lcur[dd >> LOG_SBS], 1);
            packed1[pos] = (unsigned)s.y | ((dd & (SBS - 1)) << 22);
        }
        {
            unsigned dd = (unsigned)d.z;
            int pos = atomicAdd(&lcur[dd >> LOG_SBS], 1);
            packed1[pos] = (unsigned)s.z | ((dd & (SBS - 1)) << 22);
        }
        {
            unsigned dd = (unsigned)d.w;
            int pos = atomicAdd(&lcur[dd >> LOG_SBS], 1);
            packed1[pos] = (unsigned)s.w | ((dd & (SBS - 1)) << 22);
        }
    }
    for (int e = e0 + n4 * 4 + t; e < e1; e += 256) {
        unsigned dd = (unsigned)dst0[e];
        int pos = atomicAdd(&lcur[dd >> LOG_SBS], 1);
        packed1[pos] = (unsigned)src0[e] | ((dd & (SBS - 1)) << 22);
    }
}

// ---- pass 2: per-SB node-level counting sort -> rp, dinv, compacted packed2 ----
__global__ __launch_bounds__(1024) void k_sort_sb(
    const unsigned* __restrict__ packed1, const int* __restrict__ gcur_sb,
    int* __restrict__ packed2, int* __restrict__ rp, float* __restrict__ dinv,
    int N, int NSB, int CAP) {
    __shared__ int cnt[SBS];
    __shared__ int s2[SBS];
    __shared__ int cur[SBS];
    __shared__ int sbase[NSB_MAX + 1];
    int b = blockIdx.x, t = threadIdx.x;
    // redundant per-block compaction scan over SB counts (cheap)
    if (t < NSB_MAX) sbase[t] = (t < NSB) ? (gcur_sb[t] - t * CAP) : 0;
    cnt[t] = 0;
    __syncthreads();
    if (t == 0) {
        int run = 0;
        #pragma unroll 4
        for (int i = 0; i < NSB_MAX; ++i) { int c = sbase[i]; sbase[i] = run; run += c; }
        sbase[NSB_MAX] = run;
    }
    __syncthreads();
    int cntb = gcur_sb[b] - b * CAP;
    int e0 = b * CAP, e1 = e0 + cntb;
    int obase = sbase[b];
    for (int e = e0 + t; e < e1; e += 1024)
        atomicAdd(&cnt[packed1[e] >> 22], 1);
    __syncthreads();
    int c = cnt[t];
    s2[t] = c;
    __syncthreads();
    for (int off = 1; off < 1024; off <<= 1) {
        int v = (t >= off) ? s2[t - off] : 0;
        __syncthreads();
        s2[t] += v;
        __syncthreads();
    }
    int ep = s2[t] - c;                 // exclusive prefix within SB
    int opos = obase + ep;
    cur[t] = opos;
    int node = (b << LOG_SBS) + t;
    if (node <= N) rp[node] = opos;
    if (node < N) dinv[node] = rsqrtf((float)(c + 1));   // +1 self-loop
    __syncthreads();
    for (int e = e0 + t; e < e1; e += 1024) {
        unsigned p = packed1[e];        // L2-hot re-read
        int pos = atomicAdd(&cur[p >> 22], 1);
        packed2[pos] = (int)(p & SRC_MASK);   // pure src index
    }
}

// ---- layer 1 GEMM: h1b = bf16((x@W1)*dinv) ----
__global__ __launch_bounds__(256) void k_gemm1(
    const float* __restrict__ x, const float* __restrict__ W1,
    const float* __restrict__ dinv, __hip_bfloat16* __restrict__ h1b, int N) {
    __shared__ float w[F_IN * H1];    // 8 KB
    __shared__ float xt[16 * F_IN];   // 8 KB
    int tid = threadIdx.x;
    int node0 = blockIdx.x * 16;

    const float4* W14 = (const float4*)W1;
    float4* w4 = (float4*)w;
    for (int i = tid; i < F_IN * H1 / 4; i += 256) w4[i] = W14[i];

    const float4* x4 = (const float4*)x;
    float4* xt4 = (float4*)xt;
    for (int i = tid; i < 16 * F_IN / 4; i += 256) {
        int r = i >> 5;
        int node = node0 + r;
        xt4[i] = (node < N) ? x4[(size_t)node * 32 + (i & 31)]
                            : make_float4(0.f, 0.f, 0.f, 0.f);
    }
    __syncthreads();

    int nsub = tid >> 4, f = tid & 15;
    int node = node0 + nsub;
    if (node < N) {
        const float* xr = xt + nsub * F_IN;
        float acc = 0.0f;
        #pragma unroll 16
        for (int k = 0; k < F_IN; ++k)
            acc = fmaf(xr[k], w[k * H1 + f], acc);
        h1b[(size_t)node * H1 + f] = __float2bfloat16(acc * dinv[node]);
    }
}

// ---- layer 1 aggregate + layer 2 transform, thread per (node, feature-half) ----
__global__ __launch_bounds__(256) void k_agg1(
    const int* __restrict__ packed2, const int* __restrict__ rp,
    const __hip_bfloat16* __restrict__ h1b, const float* __restrict__ dinv,
    const float* __restrict__ b1, const float* __restrict__ W2,
    float* __restrict__ h2s, int N) {
    int tid = blockIdx.x * 256 + threadIdx.x;
    int n = tid >> 1, q = tid & 1;
    if (n >= N) return;
    const uint4* h4 = (const uint4*)h1b;
    float a[8];
    {   // self-loop init: own pre-scaled row half
        uint4 s = h4[(size_t)n * 2 + q];
        a[0] = bflo(s.x); a[1] = bfhi(s.x); a[2] = bflo(s.y); a[3] = bfhi(s.y);
        a[4] = bflo(s.z); a[5] = bfhi(s.z); a[6] = bflo(s.w); a[7] = bfhi(s.w);
    }
    int e = rp[n], e1 = rp[n + 1];
    for (; e + 4 <= e1; e += 4) {
        int p0 = packed2[e + 0];
        int p1 = packed2[e + 1];
        int p2 = packed2[e + 2];
        int p3 = packed2[e + 3];
        uint4 v0 = h4[(size_t)p0 * 2 + q];
        uint4 v1 = h4[(size_t)p1 * 2 + q];
        uint4 v2 = h4[(size_t)p2 * 2 + q];
        uint4 v3 = h4[(size_t)p3 * 2 + q];
        a[0] += bflo(v0.x); a[1] += bfhi(v0.x); a[2] += bflo(v0.y); a[3] += bfhi(v0.y);
        a[4] += bflo(v0.z); a[5] += bfhi(v0.z); a[6] += bflo(v0.w); a[7] += bfhi(v0.w);
        a[0] += bflo(v1.x); a[1] += bfhi(v1.x); a[2] += bflo(v1.y); a[3] += bfhi(v1.y);
        a[4] += bflo(v1.z); a[5] += bfhi(v1.z); a[6] += bflo(v1.w); a[7] += bfhi(v1.w);
        a[0] += bflo(v2.x); a[1] += bfhi(v2.x); a[2] += bflo(v2.y); a[3] += bfhi(v2.y);
        a[4] += bflo(v2.z); a[5] += bfhi(v2.z); a[6] += bflo(v2.w); a[7] += bfhi(v2.w);
        a[0] += bflo(v3.x); a[1] += bfhi(v3.x); a[2] += bflo(v3.y); a[3] += bfhi(v3.y);
        a[4] += bflo(v3.z); a[5] += bfhi(v3.z); a[6] += bflo(v3.w); a[7] += bfhi(v3.w);
    }
    for (; e < e1; ++e) {
        int p = packed2[e];
        uint4 v = h4[(size_t)p * 2 + q];
        a[0] += bflo(v.x); a[1] += bfhi(v.x); a[2] += bflo(v.y); a[3] += bfhi(v.y);
        a[4] += bflo(v.z); a[5] += bfhi(v.z); a[6] += bflo(v.w); a[7] += bfhi(v.w);
    }
    float dv = dinv[n];
    float c0 = 0.f, c1 = 0.f;
    #pragma unroll
    for (int j = 0; j < 8; ++j) {
        int f = q * 8 + j;
        float vv = fmaxf(fmaf(a[j], dv, b1[f]), 0.f);
        c0 = fmaf(vv, W2[f * C_OUT + 0], c0);
        c1 = fmaf(vv, W2[f * C_OUT + 1], c1);
    }
    c0 += __shfl_xor(c0, 1);
    c1 += __shfl_xor(c1, 1);
    if (q == 0)
        ((float2*)h2s)[n] = make_float2(c0 * dv, c1 * dv);
}

// ---- layer 2 aggregate + log_softmax, thread per node ----
__global__ __launch_bounds__(256) void k_agg2(
    const int* __restrict__ packed2, const int* __restrict__ rp,
    const float* __restrict__ h2s, const float* __restrict__ dinv,
    const float* __restrict__ b2, float* __restrict__ out, int N) {
    int n = blockIdx.x * 256 + threadIdx.x;
    if (n >= N) return;
    const float2* h2 = (const float2*)h2s;
    float2 self = h2[n];
    float a0 = self.x, a1 = self.y;
    int e = rp[n], e1 = rp[n + 1];
    for (; e + 4 <= e1; e += 4) {
        int p0 = packed2[e + 0];
        int p1 = packed2[e + 1];
        int p2 = packed2[e + 2];
        int p3 = packed2[e + 3];
        float2 v0 = h2[p0], v1 = h2[p1], v2 = h2[p2], v3 = h2[p3];
        a0 += v0.x + v1.x + v2.x + v3.x;
        a1 += v0.y + v1.y + v2.y + v3.y;
    }
    for (; e < e1; ++e) {
        float2 v = h2[packed2[e]];
        a0 += v.x; a1 += v.y;
    }
    float dv = dinv[n];
    a0 = fmaf(a0, dv, b2[0]);
    a1 = fmaf(a1, dv, b2[1]);
    float m = fmaxf(a0, a1);
    float lse = m + logf(expf(a0 - m) + expf(a1 - m));
    ((float2*)out)[n] = make_float2(a0 - lse, a1 - lse);
}

extern "C" void kernel_launch(void* const* d_in, const int* in_sizes, int n_in,
                              void* d_out, int out_size, void* d_ws, size_t ws_size,
                              hipStream_t stream) {
    const float* x  = (const float*)d_in[0];
    const int* ei   = (const int*)d_in[1];
    const float* W1 = (const float*)d_in[2];
    const float* b1 = (const float*)d_in[3];
    const float* W2 = (const float*)d_in[4];
    const float* b2 = (const float*)d_in[5];
    float* out = (float*)d_out;

    const int N = in_sizes[0] / F_IN;     // 100000 (assumed <= 131072)
    const int E = in_sizes[1] / 2;        // 3200000
    const int* src0 = ei;
    const int* dst0 = ei + E;

    const int NSB = (N + SBS - 1) >> LOG_SBS;    // 98
    const int nblk = (E + CH1 - 1) / CH1;        // 782
    // per-SB capacity: expected (for a full SB) + 12.5% + 2048, 16-aligned
    int expSB = (int)(((long long)E << LOG_SBS) / N);
    int CAP = (expSB + expSB / 8 + 2048 + 15) & ~15;

    // workspace layout (float units), 16B-aligned chunks
    size_t off = 0;
    float* wsf = (float*)d_ws;
    auto take = [&](size_t nf) { float* p = wsf + off; off += (nf + 3) & ~(size_t)3; return p; };
    float* dinv    = take(N);
    __hip_bfloat16* h1b = (__hip_bfloat16*)take((size_t)N * H1 / 2);
    float* h2s     = take((size_t)N * C_OUT);
    unsigned* packed1 = (unsigned*)take((size_t)NSB * CAP);
    int*   packed2 = (int*)take(E);
    int*   gcur_sb = (int*)take(NSB_MAX);
    int*   rp      = (int*)take(N + 1);

    k_init<<<1, 256, 0, stream>>>(gcur_sb, rp, NSB, CAP, N, E);
    k_scat1<<<nblk, 256, 0, stream>>>(src0, dst0, gcur_sb, packed1, E, NSB);
    k_sort_sb<<<NSB, 1024, 0, stream>>>(packed1, gcur_sb, packed2, rp, dinv, N, NSB, CAP);
    k_gemm1<<<(N + 15) / 16, 256, 0, stream>>>(x, W1, dinv, h1b, N);
    k_agg1<<<(2 * N + 255) / 256, 256, 0, stream>>>(packed2, rp, h1b, dinv, b1, W2, h2s, N);
    k_agg2<<<(N + 255) / 256, 256, 0, stream>>>(packed2, rp, h2s, dinv, b2, out, N);
}

// Round 11
// 177.499 us; speedup vs baseline: 1.2528x; 1.0240x over previous
//
#include <hip/hip_runtime.h>
#include <hip/hip_bf16.h>
#include <math.h>

// GCN 2-layer forward, round-11: r10 structure (SBS=1024 super-bucket radix,
// fixed-capacity regions, register-accumulated CSR aggregation) with the
// k_sort_sb output scatter STAGED THROUGH LDS: scatter randomly into a 40KB
// LDS buffer per 256-node sub-range, then stream it to packed2 sequentially
// (full-line writes). r10 counter evidence: random-order 4B scatter within a
// 128KB region -> 5.3x write amplification (67MB vs 12.8MB useful); r8
// evidence: sequential full-line writes -> ~1x.
// Assumes N <= 131072 (NSB_MAX=128; src packed in 22 bits).

#define F_IN 128
#define H1 16
#define C_OUT 2
#define SBS 1024         // nodes per super-bucket
#define LOG_SBS 10
#define NSB_MAX 128
#define SRC_MASK 0x3FFFFF   // 22-bit src
#define CH1 4096         // edges per chunk in scat1
#define SUBR 256         // nodes per write sub-range in sort_sb
#define NPASS (SBS / SUBR)
#define LBUF_CAP 10240   // staged edges per sub-range (expected 8192, +25% ~ +22sigma)

typedef int ix4 __attribute__((ext_vector_type(4)));

__device__ __forceinline__ float bflo(unsigned u) { return __uint_as_float(u << 16); }
__device__ __forceinline__ float bfhi(unsigned u) { return __uint_as_float(u & 0xFFFF0000u); }

// ---- init: per-SB write cursors at region bases; rp[N] fallback ----
__global__ void k_init(int* __restrict__ gcur_sb, int* __restrict__ rp,
                       int NSB, int CAP, int N, int E) {
    int t = threadIdx.x;
    if (t < NSB) gcur_sb[t] = t * CAP;
    if (t == 0) rp[N] = E;
}

// ---- pass 1: chunk-scatter (src | dst_local<<22) into SB regions ----
__global__ __launch_bounds__(256) void k_scat1(
    const int* __restrict__ src0, const int* __restrict__ dst0,
    int* __restrict__ gcur_sb, unsigned* __restrict__ packed1, int E, int NSB) {
    __shared__ int hist[NSB_MAX];
    __shared__ int lcur[NSB_MAX];
    int t = threadIdx.x;
    if (t < NSB) hist[t] = 0;
    __syncthreads();
    int e0 = blockIdx.x * CH1, e1 = min(e0 + CH1, E);
    int n4 = (e1 - e0) >> 2;
    const ix4* d4 = (const ix4*)(dst0 + e0);
    const ix4* s4 = (const ix4*)(src0 + e0);
    for (int i = t; i < n4; i += 256) {
        ix4 d = __builtin_nontemporal_load(&d4[i]);
        atomicAdd(&hist[((unsigned)d.x) >> LOG_SBS], 1);
        atomicAdd(&hist[((unsigned)d.y) >> LOG_SBS], 1);
        atomicAdd(&hist[((unsigned)d.z) >> LOG_SBS], 1);
        atomicAdd(&hist[((unsigned)d.w) >> LOG_SBS], 1);
    }
    for (int e = e0 + n4 * 4 + t; e < e1; e += 256)
        atomicAdd(&hist[((unsigned)dst0[e]) >> LOG_SBS], 1);
    __syncthreads();
    if (t < NSB) {
        int h = hist[t];
        lcur[t] = h ? atomicAdd(&gcur_sb[t], h) : 0;
    }
    __syncthreads();
    for (int i = t; i < n4; i += 256) {
        ix4 d = __builtin_nontemporal_load(&d4[i]);
        ix4 s = __builtin_nontemporal_load(&s4[i]);
        {
            unsigned dd = (unsigned)d.x;
            int pos = atomicAdd(&lcur[dd >> LOG_SBS], 1);
            packed1[pos] = (unsigned)s.x | ((dd & (SBS - 1)) << 22);
        }
        {
            unsigned dd = (unsigned)d.y;
            int pos = atomicAdd(&lcur[dd >> LOG_SBS], 1);
            packed1[pos] = (unsigned)s.y | ((dd & (SBS - 1)) << 22);
        }
        {
            unsigned dd = (unsigned)d.z;
            int pos = atomicAdd(&lcur[dd >> LOG_SBS], 1);
            packed1[pos] = (unsigned)s.z | ((dd & (SBS - 1)) << 22);
        }
        {
            unsigned dd = (unsigned)d.w;
            int pos = atomicAdd(&lcur[dd >> LOG_SBS], 1);
            packed1[pos] = (unsigned)s.w | ((dd & (SBS - 1)) << 22);
        }
    }
    for (int e = e0 + n4 * 4 + t; e < e1; e += 256) {
        unsigned dd = (unsigned)dst0[e];
        int pos = atomicAdd(&lcur[dd >> LOG_SBS], 1);
        packed1[pos] = (unsigned)src0[e] | ((dd & (SBS - 1)) << 22);
    }
}

// ---- pass 2: per-SB counting sort; output staged via LDS, streamed out ----
__global__ __launch_bounds__(1024) void k_sort_sb(
    const unsigned* __restrict__ packed1, const int* __restrict__ gcur_sb,
    int* __restrict__ packed2, int* __restrict__ rp, float* __restrict__ dinv,
    int N, int NSB, int CAP) {
    __shared__ int cnt[SBS];            // 4 KB
    __shared__ int s2[SBS];             // 4 KB
    __shared__ int cur[SBS];            // 4 KB (LOCAL excl cursors within SB)
    __shared__ int sbase[NSB_MAX + 1];  // 0.5 KB
    __shared__ int lbuf[LBUF_CAP];      // 40 KB
    int b = blockIdx.x, t = threadIdx.x;
    // redundant per-block compaction scan over SB counts (cheap)
    if (t < NSB_MAX) sbase[t] = (t < NSB) ? (gcur_sb[t] - t * CAP) : 0;
    cnt[t] = 0;
    __syncthreads();
    if (t == 0) {
        int run = 0;
        #pragma unroll 4
        for (int i = 0; i < NSB_MAX; ++i) { int c = sbase[i]; sbase[i] = run; run += c; }
        sbase[NSB_MAX] = run;
    }
    __syncthreads();
    int cntb = gcur_sb[b] - b * CAP;
    int e0 = b * CAP, e1 = e0 + cntb;
    int obase = sbase[b];
    // phase A: per-node histogram
    for (int e = e0 + t; e < e1; e += 1024)
        atomicAdd(&cnt[packed1[e] >> 22], 1);
    __syncthreads();
    int c = cnt[t];
    s2[t] = c;
    __syncthreads();
    for (int off = 1; off < 1024; off <<= 1) {
        int v = (t >= off) ? s2[t - off] : 0;
        __syncthreads();
        s2[t] += v;
        __syncthreads();
    }
    int ep = s2[t] - c;                 // local exclusive prefix within SB
    cur[t] = ep;
    int node = (b << LOG_SBS) + t;
    if (node <= N) rp[node] = obase + ep;
    if (node < N) dinv[node] = rsqrtf((float)(c + 1));   // +1 self-loop
    __syncthreads();
    // phase B: 4 passes; scatter sub-range into LDS, stream out sequentially
    for (int r = 0; r < NPASS; ++r) {
        int base_r = cur[r * SUBR];                       // snapshot before atomics
        int end_r = (r + 1 < NPASS) ? cur[(r + 1) * SUBR] : cntb;
        int len_r = end_r - base_r;
        __syncthreads();
        for (int e = e0 + t; e < e1; e += 1024) {
            unsigned p = packed1[e];                      // L2-hot re-read
            int nd = (int)(p >> 22);
            if ((nd >> 8) == r) {                         // SUBR = 256
                int pos = atomicAdd(&cur[nd], 1) - base_r;
                if (pos < LBUF_CAP) lbuf[pos] = (int)(p & SRC_MASK);
            }
        }
        __syncthreads();
        int g0 = obase + base_r;
        int lim = min(len_r, LBUF_CAP);
        for (int i = t; i < lim; i += 1024)
            packed2[g0 + i] = lbuf[i];                    // sequential full lines
        __syncthreads();
    }
}

// ---- layer 1 GEMM: h1b = bf16((x@W1)*dinv) ----
__global__ __launch_bounds__(256) void k_gemm1(
    const float* __restrict__ x, const float* __restrict__ W1,
    const float* __restrict__ dinv, __hip_bfloat16* __restrict__ h1b, int N) {
    __shared__ float w[F_IN * H1];    // 8 KB
    __shared__ float xt[16 * F_IN];   // 8 KB
    int tid = threadIdx.x;
    int node0 = blockIdx.x * 16;

    const float4* W14 = (const float4*)W1;
    float4* w4 = (float4*)w;
    for (int i = tid; i < F_IN * H1 / 4; i += 256) w4[i] = W14[i];

    const float4* x4 = (const float4*)x;
    float4* xt4 = (float4*)xt;
    for (int i = tid; i < 16 * F_IN / 4; i += 256) {
        int r = i >> 5;
        int node = node0 + r;
        xt4[i] = (node < N) ? x4[(size_t)node * 32 + (i & 31)]
                            : make_float4(0.f, 0.f, 0.f, 0.f);
    }
    __syncthreads();

    int nsub = tid >> 4, f = tid & 15;
    int node = node0 + nsub;
    if (node < N) {
        const float* xr = xt + nsub * F_IN;
        float acc = 0.0f;
        #pragma unroll 16
        for (int k = 0; k < F_IN; ++k)
            acc = fmaf(xr[k], w[k * H1 + f], acc);
        h1b[(size_t)node * H1 + f] = __float2bfloat16(acc * dinv[node]);
    }
}

// ---- layer 1 aggregate + layer 2 transform, thread per (node, feature-half) ----
__global__ __launch_bounds__(256) void k_agg1(
    const int* __restrict__ packed2, const int* __restrict__ rp,
    const __hip_bfloat16* __restrict__ h1b, const float* __restrict__ dinv,
    const float* __restrict__ b1, const float* __restrict__ W2,
    float* __restrict__ h2s, int N) {
    int tid = blockIdx.x * 256 + threadIdx.x;
    int n = tid >> 1, q = tid & 1;
    if (n >= N) return;
    const uint4* h4 = (const uint4*)h1b;
    float a[8];
    {   // self-loop init: own pre-scaled row half
        uint4 s = h4[(size_t)n * 2 + q];
        a[0] = bflo(s.x); a[1] = bfhi(s.x); a[2] = bflo(s.y); a[3] = bfhi(s.y);
        a[4] = bflo(s.z); a[5] = bfhi(s.z); a[6] = bflo(s.w); a[7] = bfhi(s.w);
    }
    int e = rp[n], e1 = rp[n + 1];
    for (; e + 4 <= e1; e += 4) {
        int p0 = packed2[e + 0];
        int p1 = packed2[e + 1];
        int p2 = packed2[e + 2];
        int p3 = packed2[e + 3];
        uint4 v0 = h4[(size_t)p0 * 2 + q];
        uint4 v1 = h4[(size_t)p1 * 2 + q];
        uint4 v2 = h4[(size_t)p2 * 2 + q];
        uint4 v3 = h4[(size_t)p3 * 2 + q];
        a[0] += bflo(v0.x); a[1] += bfhi(v0.x); a[2] += bflo(v0.y); a[3] += bfhi(v0.y);
        a[4] += bflo(v0.z); a[5] += bfhi(v0.z); a[6] += bflo(v0.w); a[7] += bfhi(v0.w);
        a[0] += bflo(v1.x); a[1] += bfhi(v1.x); a[2] += bflo(v1.y); a[3] += bfhi(v1.y);
        a[4] += bflo(v1.z); a[5] += bfhi(v1.z); a[6] += bflo(v1.w); a[7] += bfhi(v1.w);
        a[0] += bflo(v2.x); a[1] += bfhi(v2.x); a[2] += bflo(v2.y); a[3] += bfhi(v2.y);
        a[4] += bflo(v2.z); a[5] += bfhi(v2.z); a[6] += bflo(v2.w); a[7] += bfhi(v2.w);
        a[0] += bflo(v3.x); a[1] += bfhi(v3.x); a[2] += bflo(v3.y); a[3] += bfhi(v3.y);
        a[4] += bflo(v3.z); a[5] += bfhi(v3.z); a[6] += bflo(v3.w); a[7] += bfhi(v3.w);
    }
    for (; e < e1; ++e) {
        int p = packed2[e];
        uint4 v = h4[(size_t)p * 2 + q];
        a[0] += bflo(v.x); a[1] += bfhi(v.x); a[2] += bflo(v.y); a[3] += bfhi(v.y);
        a[4] += bflo(v.z); a[5] += bfhi(v.z); a[6] += bflo(v.w); a[7] += bfhi(v.w);
    }
    float dv = dinv[n];
    float c0 = 0.f, c1 = 0.f;
    #pragma unroll
    for (int j = 0; j < 8; ++j) {
        int f = q * 8 + j;
        float vv = fmaxf(fmaf(a[j], dv, b1[f]), 0.f);
        c0 = fmaf(vv, W2[f * C_OUT + 0], c0);
        c1 = fmaf(vv, W2[f * C_OUT + 1], c1);
    }
    c0 += __shfl_xor(c0, 1);
    c1 += __shfl_xor(c1, 1);
    if (q == 0)
        ((float2*)h2s)[n] = make_float2(c0 * dv, c1 * dv);
}

// ---- layer 2 aggregate + log_softmax, thread per node ----
__global__ __launch_bounds__(256) void k_agg2(
    const int* __restrict__ packed2, const int* __restrict__ rp,
    const float* __restrict__ h2s, const float* __restrict__ dinv,
    const float* __restrict__ b2, float* __restrict__ out, int N) {
    int n = blockIdx.x * 256 + threadIdx.x;
    if (n >= N) return;
    const float2* h2 = (const float2*)h2s;
    float2 self = h2[n];
    float a0 = self.x, a1 = self.y;
    int e = rp[n], e1 = rp[n + 1];
    for (; e + 4 <= e1; e += 4) {
        int p0 = packed2[e + 0];
        int p1 = packed2[e + 1];
        int p2 = packed2[e + 2];
        int p3 = packed2[e + 3];
        float2 v0 = h2[p0], v1 = h2[p1], v2 = h2[p2], v3 = h2[p3];
        a0 += v0.x + v1.x + v2.x + v3.x;
        a1 += v0.y + v1.y + v2.y + v3.y;
    }
    for (; e < e1; ++e) {
        float2 v = h2[packed2[e]];
        a0 += v.x; a1 += v.y;
    }
    float dv = dinv[n];
    a0 = fmaf(a0, dv, b2[0]);
    a1 = fmaf(a1, dv, b2[1]);
    float m = fmaxf(a0, a1);
    float lse = m + logf(expf(a0 - m) + expf(a1 - m));
    ((float2*)out)[n] = make_float2(a0 - lse, a1 - lse);
}

extern "C" void kernel_launch(void* const* d_in, const int* in_sizes, int n_in,
                              void* d_out, int out_size, void* d_ws, size_t ws_size,
                              hipStream_t stream) {
    const float* x  = (const float*)d_in[0];
    const int* ei   = (const int*)d_in[1];
    const float* W1 = (const float*)d_in[2];
    const float* b1 = (const float*)d_in[3];
    const float* W2 = (const float*)d_in[4];
    const float* b2 = (const float*)d_in[5];
    float* out = (float*)d_out;

    const int N = in_sizes[0] / F_IN;     // 100000 (assumed <= 131072)
    const int E = in_sizes[1] / 2;        // 3200000
    const int* src0 = ei;
    const int* dst0 = ei + E;

    const int NSB = (N + SBS - 1) >> LOG_SBS;    // 98
    const int nblk = (E + CH1 - 1) / CH1;        // 782
    // per-SB capacity: expected (for a full SB) + 12.5% + 2048, 16-aligned
    int expSB = (int)(((long long)E << LOG_SBS) / N);
    int CAP = (expSB + expSB / 8 + 2048 + 15) & ~15;

    // workspace layout (float units), 16B-aligned chunks
    size_t off = 0;
    float* wsf = (float*)d_ws;
    auto take = [&](size_t nf) { float* p = wsf + off; off += (nf + 3) & ~(size_t)3; return p; };
    float* dinv    = take(N);
    __hip_bfloat16* h1b = (__hip_bfloat16*)take((size_t)N * H1 / 2);
    float* h2s     = take((size_t)N * C_OUT);
    unsigned* packed1 = (unsigned*)take((size_t)NSB * CAP);
    int*   packed2 = (int*)take(E);
    int*   gcur_sb = (int*)take(NSB_MAX);
    int*   rp      = (int*)take(N + 1);

    k_init<<<1, 256, 0, stream>>>(gcur_sb, rp, NSB, CAP, N, E);
    k_scat1<<<nblk, 256, 0, stream>>>(src0, dst0, gcur_sb, packed1, E, NSB);
    k_sort_sb<<<NSB, 1024, 0, stream>>>(packed1, gcur_sb, packed2, rp, dinv, N, NSB, CAP);
    k_gemm1<<<(N + 15) / 16, 256, 0, stream>>>(x, W1, dinv, h1b, N);
    k_agg1<<<(2 * N + 255) / 256, 256, 0, stream>>>(packed2, rp, h1b, dinv, b1, W2, h2s, N);
    k_agg2<<<(N + 255) / 256, 256, 0, stream>>>(packed2, rp, h2s, dinv, b2, out, N);
}

// Round 12
// 157.023 us; speedup vs baseline: 1.4161x; 1.1304x over previous
//
#include <hip/hip_runtime.h>
#include <hip/hip_bf16.h>
#include <math.h>

// GCN 2-layer forward, round-12: r11 structure with sort_sb SPLIT:
//   k_hist  (98 blocks): per-SB histogram + scan -> rp[] (all nodes), dinv[].
//   k_place (784 blocks = 8 x 128-node slices per SB): re-stream SB region
//           (L2-hot), filter own slice via rp-derived LDS cursors into a 22KB
//           LDS buffer, stream out sequentially (r11's ~1x write pattern).
//           XCD-aware bid mapping (bid%8 == sb%8) co-locates an SB's 8 slices
//           on one XCD's L2. Fixes r11's parallelism wall (98 blocks, 14% occ).
// Aggregation unchanged (register-accumulated CSR, bf16 h1 table, fused
// layer-2 transform / log_softmax). Assumes N <= 131072.

#define F_IN 128
#define H1 16
#define C_OUT 2
#define SBS 1024         // nodes per super-bucket
#define LOG_SBS 10
#define NSB_MAX 128
#define SRC_MASK 0x3FFFFF   // 22-bit src
#define CH1 4096         // edges per chunk in scat1
#define SLICE 128        // nodes per place-slice
#define NSLICE (SBS / SLICE)   // 8
#define PCAP 5632        // staged edges per slice (expected ~4096, +24 sigma)

typedef int ix4 __attribute__((ext_vector_type(4)));

__device__ __forceinline__ float bflo(unsigned u) { return __uint_as_float(u << 16); }
__device__ __forceinline__ float bfhi(unsigned u) { return __uint_as_float(u & 0xFFFF0000u); }

// ---- init: per-SB write cursors at region bases; final rp entry ----
__global__ void k_init(int* __restrict__ gcur_sb, int* __restrict__ rp,
                       int NSB, int CAP, int E) {
    int t = threadIdx.x;
    if (t < NSB) gcur_sb[t] = t * CAP;
    if (t == 0) rp[NSB * SBS] = E;
}

// ---- pass 1: chunk-scatter (src | dst_local<<22) into SB regions ----
__global__ __launch_bounds__(256) void k_scat1(
    const int* __restrict__ src0, const int* __restrict__ dst0,
    int* __restrict__ gcur_sb, unsigned* __restrict__ packed1, int E, int NSB) {
    __shared__ int hist[NSB_MAX];
    __shared__ int lcur[NSB_MAX];
    int t = threadIdx.x;
    if (t < NSB) hist[t] = 0;
    __syncthreads();
    int e0 = blockIdx.x * CH1, e1 = min(e0 + CH1, E);
    int n4 = (e1 - e0) >> 2;
    const ix4* d4 = (const ix4*)(dst0 + e0);
    const ix4* s4 = (const ix4*)(src0 + e0);
    for (int i = t; i < n4; i += 256) {
        ix4 d = __builtin_nontemporal_load(&d4[i]);
        atomicAdd(&hist[((unsigned)d.x) >> LOG_SBS], 1);
        atomicAdd(&hist[((unsigned)d.y) >> LOG_SBS], 1);
        atomicAdd(&hist[((unsigned)d.z) >> LOG_SBS], 1);
        atomicAdd(&hist[((unsigned)d.w) >> LOG_SBS], 1);
    }
    for (int e = e0 + n4 * 4 + t; e < e1; e += 256)
        atomicAdd(&hist[((unsigned)dst0[e]) >> LOG_SBS], 1);
    __syncthreads();
    if (t < NSB) {
        int h = hist[t];
        lcur[t] = h ? atomicAdd(&gcur_sb[t], h) : 0;
    }
    __syncthreads();
    for (int i = t; i < n4; i += 256) {
        ix4 d = __builtin_nontemporal_load(&d4[i]);
        ix4 s = __builtin_nontemporal_load(&s4[i]);
        {
            unsigned dd = (unsigned)d.x;
            int pos = atomicAdd(&lcur[dd >> LOG_SBS], 1);
            packed1[pos] = (unsigned)s.x | ((dd & (SBS - 1)) << 22);
        }
        {
            unsigned dd = (unsigned)d.y;
            int pos = atomicAdd(&lcur[dd >> LOG_SBS], 1);
            packed1[pos] = (unsigned)s.y | ((dd & (SBS - 1)) << 22);
        }
        {
            unsigned dd = (unsigned)d.z;
            int pos = atomicAdd(&lcur[dd >> LOG_SBS], 1);
            packed1[pos] = (unsigned)s.z | ((dd & (SBS - 1)) << 22);
        }
        {
            unsigned dd = (unsigned)d.w;
            int pos = atomicAdd(&lcur[dd >> LOG_SBS], 1);
            packed1[pos] = (unsigned)s.w | ((dd & (SBS - 1)) << 22);
        }
    }
    for (int e = e0 + n4 * 4 + t; e < e1; e += 256) {
        unsigned dd = (unsigned)dst0[e];
        int pos = atomicAdd(&lcur[dd >> LOG_SBS], 1);
        packed1[pos] = (unsigned)src0[e] | ((dd & (SBS - 1)) << 22);
    }
}

// ---- pass 2a: per-SB histogram + scan -> rp (ALL nodes of SB), dinv ----
__global__ __launch_bounds__(1024) void k_hist(
    const unsigned* __restrict__ packed1, const int* __restrict__ gcur_sb,
    int* __restrict__ rp, float* __restrict__ dinv, int N, int NSB, int CAP) {
    __shared__ int cnt[SBS];
    __shared__ int s2[SBS];
    __shared__ int sbase[NSB_MAX];
    int b = blockIdx.x, t = threadIdx.x;
    if (t < NSB_MAX) sbase[t] = (t < NSB) ? (gcur_sb[t] - t * CAP) : 0;
    cnt[t] = 0;
    __syncthreads();
    if (t == 0) {
        int run = 0;
        #pragma unroll 4
        for (int i = 0; i < NSB_MAX; ++i) { int c = sbase[i]; sbase[i] = run; run += c; }
    }
    __syncthreads();
    int cntb = gcur_sb[b] - b * CAP;
    int e0 = b * CAP, e1 = e0 + cntb;
    int obase = sbase[b];
    int n4 = cntb >> 2;
    const ix4* p4 = (const ix4*)(packed1 + e0);
    for (int i = t; i < n4; i += 1024) {
        ix4 p = p4[i];
        atomicAdd(&cnt[((unsigned)p.x) >> 22], 1);
        atomicAdd(&cnt[((unsigned)p.y) >> 22], 1);
        atomicAdd(&cnt[((unsigned)p.z) >> 22], 1);
        atomicAdd(&cnt[((unsigned)p.w) >> 22], 1);
    }
    for (int e = e0 + n4 * 4 + t; e < e1; e += 1024)
        atomicAdd(&cnt[packed1[e] >> 22], 1);
    __syncthreads();
    int c = cnt[t];
    s2[t] = c;
    __syncthreads();
    for (int off = 1; off < 1024; off <<= 1) {
        int v = (t >= off) ? s2[t - off] : 0;
        __syncthreads();
        s2[t] += v;
        __syncthreads();
    }
    int ep = s2[t] - c;                 // exclusive prefix within SB
    int node = (b << LOG_SBS) + t;
    rp[node] = obase + ep;              // defined for ALL SB nodes
    if (node < N) dinv[node] = rsqrtf((float)(c + 1));   // +1 self-loop
}

// ---- pass 2b: placement, 8 slice-blocks per SB; LDS-staged sequential out ----
__global__ __launch_bounds__(512) void k_place(
    const unsigned* __restrict__ packed1, const int* __restrict__ gcur_sb,
    const int* __restrict__ rp, int* __restrict__ packed2,
    int NSB, int PADB, int CAP) {
    __shared__ int cur[SLICE];
    __shared__ int lbuf[PCAP];
    int bid = blockIdx.x;
    int s = bid / PADB, b = bid - s * PADB;
    if (b >= NSB) return;
    int t = threadIdx.x;
    int node0 = (b << LOG_SBS) + s * SLICE;
    int g0 = rp[node0];
    if (t < SLICE) cur[t] = rp[node0 + t] - g0;
    int slice_len = rp[node0 + SLICE] - g0;
    __syncthreads();
    int cntb = gcur_sb[b] - b * CAP;
    int e0 = b * CAP, e1 = e0 + cntb;
    int n4 = cntb >> 2;
    const ix4* p4 = (const ix4*)(packed1 + e0);
    for (int i = t; i < n4; i += 512) {
        ix4 p = p4[i];
        {
            unsigned nd = ((unsigned)p.x) >> 22;
            if ((nd >> 7) == (unsigned)s) {
                int pos = atomicAdd(&cur[nd & (SLICE - 1)], 1);
                if (pos < PCAP) lbuf[pos] = p.x & SRC_MASK;
            }
        }
        {
            unsigned nd = ((unsigned)p.y) >> 22;
            if ((nd >> 7) == (unsigned)s) {
                int pos = atomicAdd(&cur[nd & (SLICE - 1)], 1);
                if (pos < PCAP) lbuf[pos] = p.y & SRC_MASK;
            }
        }
        {
            unsigned nd = ((unsigned)p.z) >> 22;
            if ((nd >> 7) == (unsigned)s) {
                int pos = atomicAdd(&cur[nd & (SLICE - 1)], 1);
                if (pos < PCAP) lbuf[pos] = p.z & SRC_MASK;
            }
        }
        {
            unsigned nd = ((unsigned)p.w) >> 22;
            if ((nd >> 7) == (unsigned)s) {
                int pos = atomicAdd(&cur[nd & (SLICE - 1)], 1);
                if (pos < PCAP) lbuf[pos] = p.w & SRC_MASK;
            }
        }
    }
    for (int e = e0 + n4 * 4 + t; e < e1; e += 512) {
        unsigned p = packed1[e];
        unsigned nd = p >> 22;
        if ((nd >> 7) == (unsigned)s) {
            int pos = atomicAdd(&cur[nd & (SLICE - 1)], 1);
            if (pos < PCAP) lbuf[pos] = (int)(p & SRC_MASK);
        }
    }
    __syncthreads();
    int lim = min(slice_len, PCAP);
    for (int i = t; i < lim; i += 512)
        packed2[g0 + i] = lbuf[i];      // sequential full-line writes
}

// ---- layer 1 GEMM: h1b = bf16((x@W1)*dinv) ----
__global__ __launch_bounds__(256) void k_gemm1(
    const float* __restrict__ x, const float* __restrict__ W1,
    const float* __restrict__ dinv, __hip_bfloat16* __restrict__ h1b, int N) {
    __shared__ float w[F_IN * H1];    // 8 KB
    __shared__ float xt[16 * F_IN];   // 8 KB
    int tid = threadIdx.x;
    int node0 = blockIdx.x * 16;

    const float4* W14 = (const float4*)W1;
    float4* w4 = (float4*)w;
    for (int i = tid; i < F_IN * H1 / 4; i += 256) w4[i] = W14[i];

    const float4* x4 = (const float4*)x;
    float4* xt4 = (float4*)xt;
    for (int i = tid; i < 16 * F_IN / 4; i += 256) {
        int r = i >> 5;
        int node = node0 + r;
        xt4[i] = (node < N) ? x4[(size_t)node * 32 + (i & 31)]
                            : make_float4(0.f, 0.f, 0.f, 0.f);
    }
    __syncthreads();

    int nsub = tid >> 4, f = tid & 15;
    int node = node0 + nsub;
    if (node < N) {
        const float* xr = xt + nsub * F_IN;
        float acc = 0.0f;
        #pragma unroll 16
        for (int k = 0; k < F_IN; ++k)
            acc = fmaf(xr[k], w[k * H1 + f], acc);
        h1b[(size_t)node * H1 + f] = __float2bfloat16(acc * dinv[node]);
    }
}

// ---- layer 1 aggregate + layer 2 transform, thread per (node, feature-half) ----
__global__ __launch_bounds__(256) void k_agg1(
    const int* __restrict__ packed2, const int* __restrict__ rp,
    const __hip_bfloat16* __restrict__ h1b, const float* __restrict__ dinv,
    const float* __restrict__ b1, const float* __restrict__ W2,
    float* __restrict__ h2s, int N) {
    int tid = blockIdx.x * 256 + threadIdx.x;
    int n = tid >> 1, q = tid & 1;
    if (n >= N) return;
    const uint4* h4 = (const uint4*)h1b;
    float a[8];
    {   // self-loop init: own pre-scaled row half
        uint4 s = h4[(size_t)n * 2 + q];
        a[0] = bflo(s.x); a[1] = bfhi(s.x); a[2] = bflo(s.y); a[3] = bfhi(s.y);
        a[4] = bflo(s.z); a[5] = bfhi(s.z); a[6] = bflo(s.w); a[7] = bfhi(s.w);
    }
    int e = rp[n], e1 = rp[n + 1];
    for (; e + 4 <= e1; e += 4) {
        int p0 = packed2[e + 0];
        int p1 = packed2[e + 1];
        int p2 = packed2[e + 2];
        int p3 = packed2[e + 3];
        uint4 v0 = h4[(size_t)p0 * 2 + q];
        uint4 v1 = h4[(size_t)p1 * 2 + q];
        uint4 v2 = h4[(size_t)p2 * 2 + q];
        uint4 v3 = h4[(size_t)p3 * 2 + q];
        a[0] += bflo(v0.x); a[1] += bfhi(v0.x); a[2] += bflo(v0.y); a[3] += bfhi(v0.y);
        a[4] += bflo(v0.z); a[5] += bfhi(v0.z); a[6] += bflo(v0.w); a[7] += bfhi(v0.w);
        a[0] += bflo(v1.x); a[1] += bfhi(v1.x); a[2] += bflo(v1.y); a[3] += bfhi(v1.y);
        a[4] += bflo(v1.z); a[5] += bfhi(v1.z); a[6] += bflo(v1.w); a[7] += bfhi(v1.w);
        a[0] += bflo(v2.x); a[1] += bfhi(v2.x); a[2] += bflo(v2.y); a[3] += bfhi(v2.y);
        a[4] += bflo(v2.z); a[5] += bfhi(v2.z); a[6] += bflo(v2.w); a[7] += bfhi(v2.w);
        a[0] += bflo(v3.x); a[1] += bfhi(v3.x); a[2] += bflo(v3.y); a[3] += bfhi(v3.y);
        a[4] += bflo(v3.z); a[5] += bfhi(v3.z); a[6] += bflo(v3.w); a[7] += bfhi(v3.w);
    }
    for (; e < e1; ++e) {
        int p = packed2[e];
        uint4 v = h4[(size_t)p * 2 + q];
        a[0] += bflo(v.x); a[1] += bfhi(v.x); a[2] += bflo(v.y); a[3] += bfhi(v.y);
        a[4] += bflo(v.z); a[5] += bfhi(v.z); a[6] += bflo(v.w); a[7] += bfhi(v.w);
    }
    float dv = dinv[n];
    float c0 = 0.f, c1 = 0.f;
    #pragma unroll
    for (int j = 0; j < 8; ++j) {
        int f = q * 8 + j;
        float vv = fmaxf(fmaf(a[j], dv, b1[f]), 0.f);
        c0 = fmaf(vv, W2[f * C_OUT + 0], c0);
        c1 = fmaf(vv, W2[f * C_OUT + 1], c1);
    }
    c0 += __shfl_xor(c0, 1);
    c1 += __shfl_xor(c1, 1);
    if (q == 0)
        ((float2*)h2s)[n] = make_float2(c0 * dv, c1 * dv);
}

// ---- layer 2 aggregate + log_softmax, thread per node ----
__global__ __launch_bounds__(256) void k_agg2(
    const int* __restrict__ packed2, const int* __restrict__ rp,
    const float* __restrict__ h2s, const float* __restrict__ dinv,
    const float* __restrict__ b2, float* __restrict__ out, int N) {
    int n = blockIdx.x * 256 + threadIdx.x;
    if (n >= N) return;
    const float2* h2 = (const float2*)h2s;
    float2 self = h2[n];
    float a0 = self.x, a1 = self.y;
    int e = rp[n], e1 = rp[n + 1];
    for (; e + 4 <= e1; e += 4) {
        int p0 = packed2[e + 0];
        int p1 = packed2[e + 1];
        int p2 = packed2[e + 2];
        int p3 = packed2[e + 3];
        float2 v0 = h2[p0], v1 = h2[p1], v2 = h2[p2], v3 = h2[p3];
        a0 += v0.x + v1.x + v2.x + v3.x;
        a1 += v0.y + v1.y + v2.y + v3.y;
    }
    for (; e < e1; ++e) {
        float2 v = h2[packed2[e]];
        a0 += v.x; a1 += v.y;
    }
    float dv = dinv[n];
    a0 = fmaf(a0, dv, b2[0]);
    a1 = fmaf(a1, dv, b2[1]);
    float m = fmaxf(a0, a1);
    float lse = m + logf(expf(a0 - m) + expf(a1 - m));
    ((float2*)out)[n] = make_float2(a0 - lse, a1 - lse);
}

extern "C" void kernel_launch(void* const* d_in, const int* in_sizes, int n_in,
                              void* d_out, int out_size, void* d_ws, size_t ws_size,
                              hipStream_t stream) {
    const float* x  = (const float*)d_in[0];
    const int* ei   = (const int*)d_in[1];
    const float* W1 = (const float*)d_in[2];
    const float* b1 = (const float*)d_in[3];
    const float* W2 = (const float*)d_in[4];
    const float* b2 = (const float*)d_in[5];
    float* out = (float*)d_out;

    const int N = in_sizes[0] / F_IN;     // 100000 (assumed <= 131072)
    const int E = in_sizes[1] / 2;        // 3200000
    const int* src0 = ei;
    const int* dst0 = ei + E;

    const int NSB = (N + SBS - 1) >> LOG_SBS;    // 98
    const int nblk = (E + CH1 - 1) / CH1;        // 782
    const int PADB = (NSB + 7) & ~7;             // 104 (x8 XCD-stable mapping)
    // per-SB capacity: expected (for a full SB) + 12.5% + 2048, 16-aligned
    int expSB = (int)(((long long)E << LOG_SBS) / N);
    int CAP = (expSB + expSB / 8 + 2048 + 15) & ~15;

    // workspace layout (float units), 16B-aligned chunks
    size_t off = 0;
    float* wsf = (float*)d_ws;
    auto take = [&](size_t nf) { float* p = wsf + off; off += (nf + 3) & ~(size_t)3; return p; };
    float* dinv    = take(N);
    __hip_bfloat16* h1b = (__hip_bfloat16*)take((size_t)N * H1 / 2);
    float* h2s     = take((size_t)N * C_OUT);
    unsigned* packed1 = (unsigned*)take((size_t)NSB * CAP);
    int*   packed2 = (int*)take(E);
    int*   gcur_sb = (int*)take(NSB_MAX);
    int*   rp      = (int*)take((size_t)NSB * SBS + 1);

    k_init<<<1, 256, 0, stream>>>(gcur_sb, rp, NSB, CAP, E);
    k_scat1<<<nblk, 256, 0, stream>>>(src0, dst0, gcur_sb, packed1, E, NSB);
    k_hist<<<NSB, 1024, 0, stream>>>(packed1, gcur_sb, rp, dinv, N, NSB, CAP);
    k_place<<<NSLICE * PADB, 512, 0, stream>>>(packed1, gcur_sb, rp, packed2, NSB, PADB, CAP);
    k_gemm1<<<(N + 15) / 16, 256, 0, stream>>>(x, W1, dinv, h1b, N);
    k_agg1<<<(2 * N + 255) / 256, 256, 0, stream>>>(packed2, rp, h1b, dinv, b1, W2, h2s, N);
    k_agg2<<<(N + 255) / 256, 256, 0, stream>>>(packed2, rp, h2s, dinv, b2, out, N);
}